// Round 1
// baseline (978.299 us; speedup 1.0000x reference)
//
#include <hip/hip_runtime.h>

#define NN 50000
#define HD 8
#define CD 64
#define NHF 512   // HD*CD

// ---------------- CSR build (by destination) ----------------
__global__ void k_init_cnt(int* __restrict__ cnt) {
    int i = blockIdx.x * 256 + threadIdx.x;
    if (i < NN) cnt[i] = 1;  // self loop contributes 1 per node
}

__global__ void k_hist(const int* __restrict__ dst, int E, int* __restrict__ cnt) {
    int e = blockIdx.x * 256 + threadIdx.x;
    if (e < E) atomicAdd(&cnt[dst[e]], 1);
}

// cnt and cursor may alias: cnt[i] is read into a local before cursor[i] is written.
__global__ __launch_bounds__(1024) void k_scan(const int* __restrict__ cnt_in,
                                               int* __restrict__ row_ptr,
                                               int* __restrict__ cursor,
                                               int* __restrict__ csr_src) {
    __shared__ int sums[1024];
    const int tid = threadIdx.x;
    const int chunk = (NN + 1023) / 1024;  // 49
    int start = tid * chunk;
    int end = min(start + chunk, NN);
    if (start > NN) start = NN;
    int s = 0;
    for (int i = start; i < end; ++i) s += cnt_in[i];
    sums[tid] = s;
    __syncthreads();
    for (int off = 1; off < 1024; off <<= 1) {
        int v = (tid >= off) ? sums[tid - off] : 0;
        __syncthreads();
        sums[tid] += v;
        __syncthreads();
    }
    int base = tid ? sums[tid - 1] : 0;
    for (int i = start; i < end; ++i) {
        int c = cnt_in[i];     // read BEFORE aliased cursor write
        row_ptr[i] = base;
        csr_src[base] = i;     // self-loop occupies first slot of each segment
        cursor[i] = base + 1;
        base += c;
    }
    if (tid == 1023) row_ptr[NN] = base;  // = E + NN
}

__global__ void k_scatter(const int* __restrict__ src, const int* __restrict__ dst,
                          int E, int* __restrict__ cursor, int* __restrict__ csr_src) {
    int e = blockIdx.x * 256 + threadIdx.x;
    if (e < E) {
        int pos = atomicAdd(&cursor[dst[e]], 1);
        csr_src[pos] = src[e];
    }
}

// ---------------- GEMM (f32, 64x64 tile, 4x4/thread) + fused alpha epilogue ----------------
__global__ __launch_bounds__(256) void k_gemm_alpha(
    const float* __restrict__ A, const float* __restrict__ B,
    const float* __restrict__ a_src, const float* __restrict__ a_dst,
    float* __restrict__ C, float* __restrict__ asrc_out, float* __restrict__ adst_out,
    int M, int K)
{
    __shared__ float As[16][64];
    __shared__ float Bs[16][64];
    const int t  = threadIdx.x;
    const int bm = blockIdx.x * 64;
    const int bn = blockIdx.y * 64;
    const int tm = (t >> 4) * 4;
    const int tn = (t & 15) * 4;

    float acc[4][4] = {};

    const int a_row = bm + (t >> 2);
    const int a_kv  = (t & 3) * 4;
    const int b_k   = (t >> 4);
    const int b_col = bn + (t & 15) * 4;

    for (int k0 = 0; k0 < K; k0 += 16) {
        float4 av = make_float4(0.f, 0.f, 0.f, 0.f);
        if (a_row < M) av = *(const float4*)(A + (size_t)a_row * K + k0 + a_kv);
        As[a_kv + 0][t >> 2] = av.x;
        As[a_kv + 1][t >> 2] = av.y;
        As[a_kv + 2][t >> 2] = av.z;
        As[a_kv + 3][t >> 2] = av.w;
        float4 bv = *(const float4*)(B + (size_t)(k0 + b_k) * NHF + b_col);
        *(float4*)(&Bs[b_k][(t & 15) * 4]) = bv;
        __syncthreads();
#pragma unroll
        for (int kk = 0; kk < 16; ++kk) {
            float4 a = *(const float4*)(&As[kk][tm]);
            float4 b = *(const float4*)(&Bs[kk][tn]);
            acc[0][0] += a.x * b.x; acc[0][1] += a.x * b.y; acc[0][2] += a.x * b.z; acc[0][3] += a.x * b.w;
            acc[1][0] += a.y * b.x; acc[1][1] += a.y * b.y; acc[1][2] += a.y * b.z; acc[1][3] += a.y * b.w;
            acc[2][0] += a.z * b.x; acc[2][1] += a.z * b.y; acc[2][2] += a.z * b.z; acc[2][3] += a.z * b.w;
            acc[3][0] += a.w * b.x; acc[3][1] += a.w * b.y; acc[3][2] += a.w * b.z; acc[3][3] += a.w * b.w;
        }
        __syncthreads();
    }

    const float4 asv = *(const float4*)(a_src + bn + tn);
    const float4 adv = *(const float4*)(a_dst + bn + tn);
    const int head = bn >> 6;
#pragma unroll
    for (int i = 0; i < 4; ++i) {
        int row = bm + tm + i;
        float4 cv = make_float4(acc[i][0], acc[i][1], acc[i][2], acc[i][3]);
        if (row < M) *(float4*)(C + (size_t)row * NHF + bn + tn) = cv;
        float ps = cv.x * asv.x + cv.y * asv.y + cv.z * asv.z + cv.w * asv.w;
        float pd = cv.x * adv.x + cv.y * adv.y + cv.z * adv.z + cv.w * adv.w;
#pragma unroll
        for (int off = 1; off < 16; off <<= 1) {
            ps += __shfl_xor(ps, off);
            pd += __shfl_xor(pd, off);
        }
        if ((t & 15) == 0 && row < M) {
            asrc_out[row * HD + head] = ps;
            adst_out[row * HD + head] = pd;
        }
    }
}

// ---------------- fused edge softmax + aggregation: one wave per dst node ----------------
__global__ __launch_bounds__(256) void k_aggregate(
    const float* __restrict__ xl, const float* __restrict__ asrc,
    const float* __restrict__ adst, const int* __restrict__ row_ptr,
    const int* __restrict__ csr_src, const float* __restrict__ bias,
    float* __restrict__ out, int relu)
{
    __shared__ float sh[4][NHF];
    const int wid  = threadIdx.x >> 6;
    const int lane = threadIdx.x & 63;
    const int n    = blockIdx.x * 4 + wid;   // NN % 4 == 0, always valid
    const int head = lane >> 3;

    const float ad = adst[n * HD + head];
    const int e0 = row_ptr[n];
    const int e1 = row_ptr[n + 1];

    float m = -1e30f, s = 0.f;
    float acc[8] = {};

    for (int e = e0; e < e1; ++e) {
        const int src = csr_src[e];
        float araw = asrc[src * HD + head] + ad;
        float a = araw > 0.f ? araw : 0.2f * araw;
        float mn = fmaxf(m, a);
        float r = __expf(m - mn);
        float p = __expf(a - mn);
        m = mn;
        s = s * r + p;
        const float4* rowp = (const float4*)(xl + (size_t)src * NHF + lane * 8);
        float4 v0 = rowp[0];
        float4 v1 = rowp[1];
        acc[0] = acc[0] * r + p * v0.x;
        acc[1] = acc[1] * r + p * v0.y;
        acc[2] = acc[2] * r + p * v0.z;
        acc[3] = acc[3] * r + p * v0.w;
        acc[4] = acc[4] * r + p * v1.x;
        acc[5] = acc[5] * r + p * v1.y;
        acc[6] = acc[6] * r + p * v1.z;
        acc[7] = acc[7] * r + p * v1.w;
    }

    const float inv = 1.f / (s + 1e-16f);
#pragma unroll
    for (int j = 0; j < 8; ++j) sh[wid][lane * 8 + j] = acc[j] * inv;
    __syncthreads();

    float sum = 0.f;
#pragma unroll
    for (int h = 0; h < HD; ++h) sum += sh[wid][h * CD + lane];
    float res = sum * 0.125f + bias[lane];
    if (relu) res = fmaxf(res, 0.f);
    out[(size_t)n * CD + lane] = res;
}

// ---------------- launch ----------------
extern "C" void kernel_launch(void* const* d_in, const int* in_sizes, int n_in,
                              void* d_out, int out_size, void* d_ws, size_t ws_size,
                              hipStream_t stream) {
    const float* x   = (const float*)d_in[0];
    const int*   ei  = (const int*)d_in[1];
    const float* W1  = (const float*)d_in[2];
    const float* as1 = (const float*)d_in[3];
    const float* ad1 = (const float*)d_in[4];
    const float* b1  = (const float*)d_in[5];
    const float* W2  = (const float*)d_in[6];
    const float* as2 = (const float*)d_in[7];
    const float* ad2 = (const float*)d_in[8];
    const float* b2  = (const float*)d_in[9];

    const int E = in_sizes[1] / 2;      // 800000
    const int* esrc = ei;
    const int* edst = ei + E;

    char* ws = (char*)d_ws;
    float* xl      = (float*)ws;                            // 102,400,000 B
    float* asrc    = (float*)(ws + 102400000);              // 1,600,000 B
    float* adst    = (float*)(ws + 104000000);              // 1,600,000 B
    float* h       = (float*)(ws + 105600000);              // 12,800,000 B
    int*   row_ptr = (int*)  (ws + 118400000);              // 200,004 B
    int*   cursor  = (int*)  (ws + 118600004);              // 200,000 B
    int*   csr_src = (int*)  (ws + 118800004);              // 3,400,000 B

    k_init_cnt<<<(NN + 255) / 256, 256, 0, stream>>>(cursor);
    k_hist<<<(E + 255) / 256, 256, 0, stream>>>(edst, E, cursor);
    k_scan<<<1, 1024, 0, stream>>>(cursor, row_ptr, cursor, csr_src);
    k_scatter<<<(E + 255) / 256, 256, 0, stream>>>(esrc, edst, E, cursor, csr_src);

    dim3 gemm_grid((NN + 63) / 64, NHF / 64);

    k_gemm_alpha<<<gemm_grid, 256, 0, stream>>>(x, W1, as1, ad1, xl, asrc, adst, NN, 256);
    k_aggregate<<<NN / 4, 256, 0, stream>>>(xl, asrc, adst, row_ptr, csr_src, b1, h, 1);

    k_gemm_alpha<<<gemm_grid, 256, 0, stream>>>(h, W2, as2, ad2, xl, asrc, adst, NN, 64);
    k_aggregate<<<NN / 4, 256, 0, stream>>>(xl, asrc, adst, row_ptr, csr_src, b2, (float*)d_out, 0);
}